// Round 5
// baseline (49.467 us; speedup 1.0000x reference)
//
#include <hip/hip_runtime.h>
#include <hip/hip_bf16.h>

#define CSTF 1.676543f
#define NREP 16

typedef __bf16 bf16x8 __attribute__((ext_vector_type(8)));
typedef float  f32x4  __attribute__((ext_vector_type(4)));

__device__ __forceinline__ float silu_n(float y) {
    return CSTF * y * __builtin_amdgcn_rcpf(1.0f + __expf(-y));
}

struct XG { f32x4 a, b, c, d; };

__device__ __forceinline__ XG loadx(const float* p) {
    XG r;
    r.a = *(const f32x4*)(p);
    r.b = *(const f32x4*)(p + 4);
    r.c = *(const f32x4*)(p + 32);
    r.d = *(const f32x4*)(p + 36);
    return r;
}

// Process one 16-atom group (cur = x fragment data), vb = this lane's 4 batch
// indices (atoms gi*16 + 4g + 0..3).
#define PROC16(cur, vb) { \
  bf16x8 a0, a1; \
  _Pragma("unroll") \
  for (int j = 0; j < 4; ++j) { \
    a0[j] = (__bf16)cur.a[j]; a0[j+4] = (__bf16)cur.b[j]; \
    a1[j] = (__bf16)cur.c[j]; a1[j+4] = (__bf16)cur.d[j]; \
  } \
  const f32x4 zf = {0.f, 0.f, 0.f, 0.f}; \
  _Pragma("unroll") \
  for (int nt = 0; nt < 4; ++nt) { \
    f32x4 acc = __builtin_amdgcn_mfma_f32_16x16x32_bf16(a0, wf0[0][nt], zf, 0, 0, 0); \
    acc = __builtin_amdgcn_mfma_f32_16x16x32_bf16(a1, wf0[1][nt], acc, 0, 0, 0); \
    _Pragma("unroll") \
    for (int r = 0; r < 4; ++r) \
      sb[w][4*g + r][nt*16 + c] = __float2bfloat16(silu_n(acc[r])); \
  } \
  const bf16x8 sa0 = *(const bf16x8*)&sb[w][c][g*8]; \
  const bf16x8 sa1 = *(const bf16x8*)&sb[w][c][g*8 + 32]; \
  _Pragma("unroll") \
  for (int nt = 0; nt < 4; ++nt) { \
    f32x4 z = __builtin_amdgcn_mfma_f32_16x16x32_bf16(sa0, wf1[0][nt], zf, 0, 0, 0); \
    z = __builtin_amdgcn_mfma_f32_16x16x32_bf16(sa1, wf1[1][nt], z, 0, 0, 0); \
    atomicAdd(&Srep[(vb.x << 6) + nt*16 + c], silu_n(z[0])); \
    atomicAdd(&Srep[(vb.y << 6) + nt*16 + c], silu_n(z[1])); \
    atomicAdd(&Srep[(vb.z << 6) + nt*16 + c], silu_n(z[2])); \
    atomicAdd(&Srep[(vb.w << 6) + nt*16 + c], silu_n(z[3])); \
  } \
}

// Phase 1: s2 = silu(silu(x@W0*.125)@W1*.125) via bf16 MFMA, atomic-accumulated
// into NREP replicated S[512][64] tables. 32 atoms per wave; all loads for the
// wave issued before any compute (max outstanding bytes).
__global__ __launch_bounds__(256, 3) void phase1(
    const float* __restrict__ x, const int* __restrict__ bidx,
    const float* __restrict__ W0, const float* __restrict__ W1,
    float* __restrict__ S)
{
    __shared__ __align__(16) __hip_bfloat16 sb[4][16][72];  // per-wave 16x64 (+pad)
    const int tid  = threadIdx.x;
    const int lane = tid & 63;
    const int w    = tid >> 6;
    const int c    = lane & 15;   // fragment col / row-within-16
    const int g    = lane >> 4;   // k-group

    const int wbase = (blockIdx.x * 4 + w) * 32;     // 32 atoms per wave
    const float* px = x + (size_t)(wbase + c) * 1024 + g * 8;

    // issue ALL loads up front: 8x dwordx4 of x + 2x int4 of bidx
    XG c0 = loadx(px);
    XG c1 = loadx(px + 16 * 1024);
    const int4 vb0 = *(const int4*)&bidx[wbase + 4 * g];        // atoms 4g+0..3
    const int4 vb1 = *(const int4*)&bidx[wbase + 16 + 4 * g];   // atoms 16+4g+0..3

    // Preload W0/W1 as B-fragments (K=64 in 2 k-steps, N=64 in 4 n-tiles),
    // 1/sqrt(64) norm folded into the bf16 weights. (L2/L3-hot after block 0.)
    bf16x8 wf0[2][4], wf1[2][4];
#pragma unroll
    for (int ks = 0; ks < 2; ++ks)
#pragma unroll
        for (int nt = 0; nt < 4; ++nt) {
            bf16x8 f0, f1;
#pragma unroll
            for (int j = 0; j < 8; ++j) {
                const int k = ks * 32 + g * 8 + j;
                f0[j] = (__bf16)(0.125f * W0[k * 256 + nt * 16 + c]);
                f1[j] = (__bf16)(0.125f * W1[k * 256 + nt * 16 + c]);
            }
            wf0[ks][nt] = f0;
            wf1[ks][nt] = f1;
        }

    float* Srep = S + ((size_t)(blockIdx.x & (NREP - 1)) << 15);

    PROC16(c0, vb0);
    PROC16(c1, vb1);
}

// out[b, t] = 0.125 * sum_o (sum_r S_r[b,o]) * Wout[o, t]
__global__ __launch_bounds__(128) void phase2(
    const float* __restrict__ S, const float* __restrict__ Wout,
    float* __restrict__ out)
{
    __shared__ float sp[64];
    const int b = blockIdx.x, t = threadIdx.x;
    if (t < 64) {
        float s = 0.f;
#pragma unroll
        for (int r = 0; r < NREP; ++r) s += S[((size_t)r << 15) + (b << 6) + t];
        sp[t] = s;
    }
    __syncthreads();
    float acc = 0.f;
#pragma unroll
    for (int o = 0; o < 64; ++o) acc = fmaf(sp[o], Wout[o * 128 + t], acc);
    out[b * 128 + t] = 0.125f * acc;
}

extern "C" void kernel_launch(void* const* d_in, const int* in_sizes, int n_in,
                              void* d_out, int out_size, void* d_ws, size_t ws_size,
                              hipStream_t stream)
{
    const float* x    = (const float*)d_in[0];
    const int*   bidx = (const int*)d_in[1];
    const float* W0   = (const float*)d_in[3];   // W0_0 (64,256)
    const float* W1   = (const float*)d_in[7];   // W1_0 (64,256)
    const float* Wout = (const float*)d_in[11];  // W_out (64,128)
    float* S   = (float*)d_ws;                    // NREP replicas of 512x64
    float* out = (float*)d_out;

    hipMemsetAsync(S, 0, (size_t)NREP * 32768 * sizeof(float), stream);
    hipLaunchKernelGGL(phase1, dim3(1024), dim3(256), 0, stream, x, bidx, W0, W1, S);
    hipLaunchKernelGGL(phase2, dim3(512), dim3(128), 0, stream, S, Wout, out);
}